// Round 4
// baseline (269.504 us; speedup 1.0000x reference)
//
#include <hip/hip_runtime.h>
#include <hip/hip_bf16.h>
#include <hip/hip_cooperative_groups.h>

namespace cg = cooperative_groups;

// Shapes (fixed): B=4, H=56, W=56, C=256, NH=8, HD=32, KS=7, PAD=3
// tokens M = 4*56*56 = 12544. Padded k/v planes: [4][64][64][256] bf16,
// interior token (y,x) at plane row y+3, col x+3; border zeroed in phase 1.
//
// R12: LDS-free direct-fragment GEMM regressed; keep LDS staging.
// R15: attn v-path de-LDS'd -- neutral; kept (lower LDS, 1 vmcnt drain).
// R16: dot2 QK + bf16 qf + packed-f32 PV: 139.8 -> 133.0 (VALU + traffic).
// R17: 2 tokens/wave (2x occupancy, +27% VALU): NEUTRAL -> attn not
//      latency-bound. Per-kernel floors sum to ~25-30us vs 133 measured ->
//      ~100us is inter-kernel overhead (launch, dispatch ramp, drain/tail).
// R18 (this round): ONE persistent cooperative kernel, grid-stride phases +
//      grid.sync() between. Phase bodies are the verified R17 code. Border-
//      zero moved beside the qkv GEMM (disjoint kp/vp writes) to use idle
//      blocks. Fallback to the 4-kernel path if cooperative launch is
//      unavailable (queried once via device attribute + occupancy).

using frag_ab = __attribute__((ext_vector_type(8))) short;  // 8 bf16 (4 VGPRs)
using f32x4   = __attribute__((ext_vector_type(4))) float;  // 4 fp32 acc
using f32x2   = __attribute__((ext_vector_type(2))) float;  // packed f32 pair

typedef const __attribute__((address_space(1))) unsigned int* gas_u32;
typedef __attribute__((address_space(3))) unsigned int*       las_u32;

__device__ __forceinline__ void gl_lds16(const void* g, void* l) {
    // async global->LDS DMA, 16 B/lane; LDS dst = wave-uniform base + lane*16
    __builtin_amdgcn_global_load_lds((gas_u32)g, (las_u32)l, 16, 0, 0);
}

__device__ __forceinline__ float bflo(unsigned int u) { return __uint_as_float(u << 16); }
__device__ __forceinline__ float bfhi(unsigned int u) { return __uint_as_float(u & 0xffff0000u); }

__device__ __forceinline__ f32x2 unpk2(unsigned int u) {
    f32x2 r; r.x = bflo(u); r.y = bfhi(u); return r;
}

#if defined(__has_builtin)
#if __has_builtin(__builtin_amdgcn_fdot2_f32_bf16)
#define HAVE_FDOT2_BF16 1
#endif
#endif

#ifdef HAVE_FDOT2_BF16
typedef __bf16 bf16x2 __attribute__((ext_vector_type(2)));
__device__ __forceinline__ float dot2bf(unsigned int a, unsigned int b, float c) {
    union { unsigned int u; bf16x2 h; } ua, ub;
    ua.u = a; ub.u = b;
    return __builtin_amdgcn_fdot2_f32_bf16(ua.h, ub.h, c, false);
}
#endif

// ===================== phase bodies (shared by fused + fallback) ============

// prep work, virtual blocks [0,4160): x->bf16 (3136), wqkvT (768), wprojT (256)
__device__ __forceinline__ void prep_body(
    int bid, int tid,
    const float* __restrict__ x,      __hip_bfloat16* __restrict__ xb,
    const float* __restrict__ w_qkv,  __hip_bfloat16* __restrict__ wqkvT,
    const float* __restrict__ w_proj, __hip_bfloat16* __restrict__ wprojT)
{
    if (bid < 3136) {
        const int i = bid * 256 + tid;            // over M*256/4 = 802816
        const float4 v = ((const float4*)x)[i];
        union { ushort4 u; __hip_bfloat16 h[4]; } o;
        o.h[0] = __float2bfloat16(v.x); o.h[1] = __float2bfloat16(v.y);
        o.h[2] = __float2bfloat16(v.z); o.h[3] = __float2bfloat16(v.w);
        ((ushort4*)xb)[i] = o.u;
    } else if (bid < 3904) {
        const int idx = (bid - 3136) * 256 + tid; // over 768*256
        const int k = idx & 255, n = idx >> 8;
        wqkvT[idx] = __float2bfloat16(w_qkv[k * 768 + n]);
    } else {
        const int idx = (bid - 3904) * 256 + tid; // over 256*256
        const int k = idx & 255, n = idx >> 8;
        wprojT[idx] = __float2bfloat16(w_proj[k * 256 + n]);
    }
}

// pad-border zero of kp/vp, virtual blocks [0,960)
__device__ __forceinline__ void border_body(
    int vb, int tid, __hip_bfloat16* __restrict__ kp, __hip_bfloat16* __restrict__ vp)
{
    const int u    = vb * 256 + tid;             // over 8*30720
    const int ip   = u / 30720;                  // img*2 + plane
    const int rem  = u - ip * 30720;
    const int cloc = rem >> 5;                   // 0..959 border cells
    const int q16  = rem & 31;                   // 16B chunk of 256 ch
    const int img  = ip >> 1;
    __hip_bfloat16* base = (ip & 1) ? vp : kp;
    int prow, pcol;
    if (cloc < 512) {                            // full pad rows 0-2,59-63
        const int r8 = cloc >> 6;
        prow = (r8 < 3) ? r8 : r8 + 56;
        pcol = cloc & 63;
    } else {                                     // side pads of rows 3..58
        const int c2 = cloc - 512;
        prow = 3 + (c2 >> 3);
        const int cc = c2 & 7;
        pcol = (cc < 3) ? cc : cc + 56;
    }
    *(uint4*)(base + (((size_t)(img * 64 + prow)) * 64 + pcol) * 256 + q16 * 8) =
        make_uint4(0u, 0u, 0u, 0u);
}

// 128x128 bf16 MFMA GEMM block (qkv): N=768; cols 0-255 -> qf bf16 (scaled);
// 256-511 -> kp; 512-767 -> vp. 256 thr = 4 waves; wave w owns quadrant.
__device__ __forceinline__ void qkv_body(
    frag_ab (*As)[64], frag_ab (*Bs)[64], int tid, int m0, int n0,
    const __hip_bfloat16* __restrict__ A,
    const __hip_bfloat16* __restrict__ BT,
    const float* __restrict__ bias,
    __hip_bfloat16* __restrict__ qf,
    __hip_bfloat16* __restrict__ kp,
    __hip_bfloat16* __restrict__ vp,
    float qscale)
{
    constexpr int K = 256;
    const int lane = tid & 63;
    const int w    = tid >> 6;
    const int wm   = w >> 1, wn = w & 1;
    const int lrow = lane & 15;
    const int lk   = (lane >> 4) * 8;
    const __hip_bfloat16* gA0 = A  + (size_t)(m0 + (2*w+0)*16 + lrow) * K + lk;
    const __hip_bfloat16* gA1 = A  + (size_t)(m0 + (2*w+1)*16 + lrow) * K + lk;
    const __hip_bfloat16* gB0 = BT + (size_t)(n0 + (2*w+0)*16 + lrow) * K + lk;
    const __hip_bfloat16* gB1 = BT + (size_t)(n0 + (2*w+1)*16 + lrow) * K + lk;
    f32x4 acc[4][4] = {};
    for (int k0 = 0; k0 < K; k0 += 32) {
        gl_lds16(gA0 + k0, &As[2*w+0][0]);
        gl_lds16(gA1 + k0, &As[2*w+1][0]);
        gl_lds16(gB0 + k0, &Bs[2*w+0][0]);
        gl_lds16(gB1 + k0, &Bs[2*w+1][0]);
        __syncthreads();
        frag_ab af[4], bf[4];
        #pragma unroll
        for (int i = 0; i < 4; ++i) { af[i] = As[wm*4+i][lane]; bf[i] = Bs[wn*4+i][lane]; }
        #pragma unroll
        for (int i = 0; i < 4; ++i)
            #pragma unroll
            for (int j = 0; j < 4; ++j)
                acc[i][j] = __builtin_amdgcn_mfma_f32_16x16x32_bf16(af[i], bf[j], acc[i][j], 0, 0, 0);
        __syncthreads();
    }
    const int rbase = (lane >> 4) * 4;
    const int cbase = lane & 15;
    #pragma unroll
    for (int fi = 0; fi < 4; ++fi) {
        const int rm = m0 + wm * 64 + fi * 16 + rbase;
        #pragma unroll
        for (int fj = 0; fj < 4; ++fj) {
            const int cn = n0 + wn * 64 + fj * 16 + cbase;
            const float bv = bias[cn];
            #pragma unroll
            for (int r = 0; r < 4; ++r) {
                const int mm  = rm + r;
                const float val = acc[fi][fj][r] + bv;
                const int sel = cn >> 8;                   // 0=q,1=k,2=v
                if (sel == 0) {
                    qf[(size_t)mm * 256 + cn] = __float2bfloat16(val * qscale);
                } else {
                    const int c  = cn & 255;
                    const int bb = mm / 3136;
                    const int r2 = mm % 3136;
                    const int yy = r2 / 56;
                    const int xx = r2 % 56;
                    __hip_bfloat16* dst = (sel == 1) ? kp : vp;
                    dst[(((size_t)(bb * 64 + yy + 3)) * 64 + (xx + 3)) * 256 + c] =
                        __float2bfloat16(val);
                }
            }
        }
    }
}

// 64x64 proj GEMM block (R2/R14-validated structure)
__device__ __forceinline__ void proj_body(
    frag_ab (*As)[64], frag_ab (*Bs)[64], int tid, int m0, int n0,
    const __hip_bfloat16* __restrict__ A,
    const __hip_bfloat16* __restrict__ BT,
    const float* __restrict__ bias,
    float* __restrict__ C)
{
    constexpr int K = 256;
    const int lane = tid & 63;
    const int w    = tid >> 6;
    const int wm   = w >> 1, wn = w & 1;
    const int lrow = lane & 15;
    const int lk   = (lane >> 4) * 8;
    const __hip_bfloat16* gA = A  + (size_t)(m0 + w * 16 + lrow) * K + lk;
    const __hip_bfloat16* gB = BT + (size_t)(n0 + w * 16 + lrow) * K + lk;
    f32x4 acc[2][2] = {};
    for (int k0 = 0; k0 < K; k0 += 32) {
        gl_lds16(gA + k0, &As[w][0]);
        gl_lds16(gB + k0, &Bs[w][0]);
        __syncthreads();
        const frag_ab a0 = As[2 * wm + 0][lane];
        const frag_ab a1 = As[2 * wm + 1][lane];
        const frag_ab b0 = Bs[2 * wn + 0][lane];
        const frag_ab b1 = Bs[2 * wn + 1][lane];
        acc[0][0] = __builtin_amdgcn_mfma_f32_16x16x32_bf16(a0, b0, acc[0][0], 0, 0, 0);
        acc[0][1] = __builtin_amdgcn_mfma_f32_16x16x32_bf16(a0, b1, acc[0][1], 0, 0, 0);
        acc[1][0] = __builtin_amdgcn_mfma_f32_16x16x32_bf16(a1, b0, acc[1][0], 0, 0, 0);
        acc[1][1] = __builtin_amdgcn_mfma_f32_16x16x32_bf16(a1, b1, acc[1][1], 0, 0, 0);
        __syncthreads();
    }
    const int rbase = (lane >> 4) * 4;
    const int cbase = lane & 15;
    #pragma unroll
    for (int fi = 0; fi < 2; ++fi) {
        const int rm = m0 + wm * 32 + fi * 16 + rbase;
        #pragma unroll
        for (int fj = 0; fj < 2; ++fj) {
            const int cn = n0 + wn * 32 + fj * 16 + cbase;
            const float bv = bias[cn];
            #pragma unroll
            for (int r = 0; r < 4; ++r)
                C[(size_t)(rm + r) * 256 + cn] = acc[fi][fj][r] + bv;
        }
    }
}

// attn wave body (R17): 2 tokens x 8 heads x 4 quarter-heads, seg in [0,6272)
// EXPLICIT SCALAR staging (R10/R11 SROA lesson); rolled ky (#pragma unroll 1;
// R8/R9 spill lesson). kbuf = 4KB wave-private LDS; srpb shared (read-only).
#define GLOAD4(plane, ky, d0, d1, d2, d3)                                       \
    do {                                                                        \
        const char* rb_ = (const char*)((plane) +                               \
            ((size_t)(prow0 + (ky)) * 64 + x0) * 256 + lane * 8);               \
        d0 = *(const uint4*)(rb_);                                              \
        d1 = *(const uint4*)(rb_ + 1024);                                       \
        d2 = *(const uint4*)(rb_ + 2048);                                       \
        d3 = *(const uint4*)(rb_ + 3072);                                       \
    } while (0)

#define LWRITE4(buf, s0, s1, s2, s3)                                            \
    do {                                                                        \
        char* wb_ = (char*)(buf) + wroff;                                       \
        *(uint4*)(wb_)        = s0;                                             \
        *(uint4*)(wb_ + 1024) = s1;                                             \
        *(uint4*)(wb_ + 2048) = s2;                                             \
        *(uint4*)(wb_ + 3072) = s3;                                             \
    } while (0)

__device__ __forceinline__ void attn_wave_body(
    int lane, int seg, __hip_bfloat16* kbuf, const float* srpb,
    const __hip_bfloat16* __restrict__ qf,
    const __hip_bfloat16* __restrict__ kp,
    const __hip_bfloat16* __restrict__ vp,
    __hip_bfloat16* __restrict__ out)
{
    const int q8   = lane & 3;          // quarter-head: 8-ch slice
    const int h    = (lane >> 2) & 7;   // head
    const int tl   = (lane >> 5) & 1;   // token within 2-token segment

    const int row = seg / 28;           // b*56 + y
    const int x0  = (seg % 28) * 2;     // 0..54
    const int b   = row / 56;
    const int y   = row % 56;
    const int t   = row * 56 + x0 + tl;
    const int prow0 = b * 64 + y;       // padded plane row for ky=0

    // q: 8 bf16 channels, kept PACKED (4 uints)
    unsigned int qpk[4];
    {
        const uint4 qa = *(const uint4*)(qf + (size_t)t * 256 + h * 32 + q8 * 8);
        qpk[0] = qa.x; qpk[1] = qa.y; qpk[2] = qa.z; qpk[3] = qa.w;
    }
#ifndef HAVE_FDOT2_BF16
    f32x2 q2[4];
    #pragma unroll
    for (int i = 0; i < 4; ++i) q2[i] = unpk2(qpk[i]);
#endif

    const int wroff = lane * 16;                    // linear LDS write
    const int rdoff = tl * 512 + h * 64 + q8 * 16;  // + kx*512 per window col

    const float* rp = &srpb[h * 49];
    float m = -1e30f, l = 0.f;
    f32x2 o2[4] = {};

    uint4 k0, k1, k2, k3;
    GLOAD4(kp, 0, k0, k1, k2, k3);

    #pragma unroll 1
    for (int ky = 0; ky < 7; ++ky) {
        LWRITE4(kbuf, k0, k1, k2, k3);          // waits vmcnt for k row only
        // per-lane direct v loads: this lane's 8 ch for its 7 cols (R15)
        const __hip_bfloat16* vrow = vp +
            ((size_t)(prow0 + ky) * 64 + x0 + tl) * 256 + h * 32 + q8 * 8;
        uint4 va[7];
        #pragma unroll
        for (int kx = 0; kx < 7; ++kx)
            va[kx] = *(const uint4*)(vrow + kx * 256);
        // k-prefetch AFTER v loads: PV's vmcnt waits never drain it
        if (ky < 6) GLOAD4(kp, ky + 1, k0, k1, k2, k3);
        // ---- 7 row logits from kbuf ----
        float lg[7];
        #pragma unroll
        for (int kx = 0; kx < 7; ++kx) {
            const uint4 w0 = *(const uint4*)((const char*)kbuf + rdoff + kx * 512);
#ifdef HAVE_FDOT2_BF16
            float s = 0.f;
            s = dot2bf(qpk[0], w0.x, s);
            s = dot2bf(qpk[1], w0.y, s);
            s = dot2bf(qpk[2], w0.z, s);
            s = dot2bf(qpk[3], w0.w, s);
#else
            f32x2 s2 = {0.f, 0.f};
            s2 += q2[0] * unpk2(w0.x);
            s2 += q2[1] * unpk2(w0.y);
            s2 += q2[2] * unpk2(w0.z);
            s2 += q2[3] * unpk2(w0.w);
            const float s = s2.x + s2.y;
#endif
            lg[kx] = s;
        }
        // ---- merge quarter-head partials (lanes ^1, ^2) + rpb ----
        #pragma unroll
        for (int kx = 0; kx < 7; ++kx) {
            lg[kx] += __shfl_xor(lg[kx], 1, 64);
            lg[kx] += __shfl_xor(lg[kx], 2, 64);
            lg[kx] += rp[ky * 7 + kx];
        }
        // ---- online softmax update ----
        float rmax = lg[0];
        #pragma unroll
        for (int kx = 1; kx < 7; ++kx) rmax = fmaxf(rmax, lg[kx]);
        const float mnew  = fmaxf(m, rmax);
        const float alpha = __expf(m - mnew);   // ky=0: exp(-inf)=0
        m = mnew;
        l *= alpha;
        const f32x2 alpha2 = {alpha, alpha};
        #pragma unroll
        for (int i = 0; i < 4; ++i) o2[i] *= alpha2;
        // ---- PV from direct-loaded registers, packed-f32 accumulate ----
        #pragma unroll
        for (int kx = 0; kx < 7; ++kx) {
            const float pr = __expf(lg[kx] - mnew);
            l += pr;
            const f32x2 pr2 = {pr, pr};
            const uint4 w0 = va[kx];
            o2[0] += pr2 * unpk2(w0.x);
            o2[1] += pr2 * unpk2(w0.y);
            o2[2] += pr2 * unpk2(w0.z);
            o2[3] += pr2 * unpk2(w0.w);
        }
    }

    // ---- store bf16 (feeds proj GEMM) ----
    const float inv = 1.f / l;
    union { uint4 u; __hip_bfloat16 hh[8]; } ob;
    #pragma unroll
    for (int i = 0; i < 4; ++i) {
        ob.hh[2 * i + 0] = __float2bfloat16(o2[i].x * inv);
        ob.hh[2 * i + 1] = __float2bfloat16(o2[i].y * inv);
    }
    *(uint4*)(out + (size_t)t * 256 + h * 32 + q8 * 8) = ob.u;
}

#undef GLOAD4
#undef LWRITE4

// ===================== fused persistent cooperative kernel ==================
struct FParams {
    const float* x; const float* w_qkv; const float* b_qkv; const float* rpb;
    const float* w_proj; const float* b_proj; float* out;
    __hip_bfloat16 *xb, *qf, *kp, *vp, *attnb, *wqkvT, *wprojT;
    float qscale;
};

// LDS plan (18432 B): phase1/3 GEMM As+Bs in [0,16384); phase2 kbuf[w] at
// w*4096 in [0,16384) + srpb(1568 B) at 16384. Phases separated by grid.sync.
__global__ __launch_bounds__(256) void fused_na2d(FParams p)
{
    __shared__ __align__(16) char smem[18432];
    const int tid = threadIdx.x;
    cg::grid_group grid = cg::this_grid();

    // ---- phase 0: x->bf16 + weight transposes (4160 virtual blocks) ----
    for (int vb = blockIdx.x; vb < 4160; vb += gridDim.x)
        prep_body(vb, tid, p.x, p.xb, p.w_qkv, p.wqkvT, p.w_proj, p.wprojT);
    grid.sync();

    // ---- phase 1: border zero (960) + qkv GEMM (588), disjoint writes ----
    {
        frag_ab (*As)[64] = (frag_ab(*)[64])(smem);
        frag_ab (*Bs)[64] = (frag_ab(*)[64])(smem + 8192);
        for (int vb = blockIdx.x; vb < 1548; vb += gridDim.x) {
            if (vb < 960) {
                border_body(vb, tid, p.kp, p.vp);
            } else {
                const int vq = vb - 960;         // 0..587 = 98 x 6
                qkv_body(As, Bs, tid, (vq / 6) * 128, (vq % 6) * 128,
                         p.xb, p.wqkvT, p.b_qkv, p.qf, p.kp, p.vp, p.qscale);
            }
        }
    }
    grid.sync();

    // ---- phase 2: attn, 1568 groups x 4 waves (seg in [0,6272)) ----
    {
        __hip_bfloat16* kbufw = (__hip_bfloat16*)(smem + (tid >> 6) * 4096);
        float* srpb = (float*)(smem + 16384);
        for (int i = tid; i < 8 * 49; i += 256) srpb[i] = p.rpb[i];
        __syncthreads();
        const int w = tid >> 6, lane = tid & 63;
        // XCD-aligned mapping: gridDim %8==0 -> vg&7 == blockIdx&7 == XCD;
        // each XCD covers a contiguous 784-seg chunk of the k/v planes.
        for (int vg = blockIdx.x; vg < 1568; vg += gridDim.x) {
            const int seg = (vg & 7) * 784 + (vg >> 3) * 4 + w;
            attn_wave_body(lane, seg, kbufw, srpb, p.qf, p.kp, p.vp, p.attnb);
        }
    }
    grid.sync();

    // ---- phase 3: proj GEMM (784 virtual blocks of 64x64) ----
    {
        frag_ab (*As)[64] = (frag_ab(*)[64])(smem);
        frag_ab (*Bs)[64] = (frag_ab(*)[64])(smem + 4096);
        for (int vb = blockIdx.x; vb < 784; vb += gridDim.x)
            proj_body(As, Bs, tid, (vb >> 2) * 64, (vb & 3) * 64,
                      p.attnb, p.wprojT, p.b_proj, p.out);
    }
}

// ===================== fallback kernels (old 4-launch path) =================
__global__ __launch_bounds__(256) void prep_k(
    const float* __restrict__ x,      __hip_bfloat16* __restrict__ xb,
    const float* __restrict__ w_qkv,  __hip_bfloat16* __restrict__ wqkvT,
    const float* __restrict__ w_proj, __hip_bfloat16* __restrict__ wprojT,
    __hip_bfloat16* __restrict__ kp,  __hip_bfloat16* __restrict__ vp)
{
    const int bid = blockIdx.x;
    if (bid < 4160) prep_body(bid, threadIdx.x, x, xb, w_qkv, wqkvT, w_proj, wprojT);
    else            border_body(bid - 4160, threadIdx.x, kp, vp);
}

__global__ __launch_bounds__(256) void gemm_qkv_k(
    const __hip_bfloat16* __restrict__ A, const __hip_bfloat16* __restrict__ BT,
    const float* __restrict__ bias, __hip_bfloat16* __restrict__ qf,
    __hip_bfloat16* __restrict__ kp, __hip_bfloat16* __restrict__ vp, float qscale)
{
    __shared__ frag_ab As[8][64];
    __shared__ frag_ab Bs[8][64];
    qkv_body(As, Bs, threadIdx.x, blockIdx.y * 128, blockIdx.x * 128,
             A, BT, bias, qf, kp, vp, qscale);
}

__global__ __launch_bounds__(256) void gemm_proj_k(
    const __hip_bfloat16* __restrict__ A, const __hip_bfloat16* __restrict__ BT,
    const float* __restrict__ bias, float* __restrict__ C)
{
    __shared__ frag_ab As[4][64];
    __shared__ frag_ab Bs[4][64];
    proj_body(As, Bs, threadIdx.x, blockIdx.y * 64, blockIdx.x * 64, A, BT, bias, C);
}

__global__ __launch_bounds__(64) void na2d_attn_k(
    const __hip_bfloat16* __restrict__ qf, const __hip_bfloat16* __restrict__ kp,
    const __hip_bfloat16* __restrict__ vp, const float* __restrict__ rpb,
    __hip_bfloat16* __restrict__ out)
{
    __shared__ __hip_bfloat16 kbuf[8 * 256];
    __shared__ float srpb[8 * 49];
    for (int i = threadIdx.x; i < 8 * 49; i += 64) srpb[i] = rpb[i];
    __syncthreads();
    const int bid = blockIdx.x;
    const int seg = (bid & 7) * 784 + (bid >> 3);   // XCD-contiguous remap
    attn_wave_body(threadIdx.x, seg, kbuf, srpb, qf, kp, vp, out);
}

// ===================== host =====================
extern "C" void kernel_launch(void* const* d_in, const int* in_sizes, int n_in,
                              void* d_out, int out_size, void* d_ws, size_t ws_size,
                              hipStream_t stream)
{
    const float* x      = (const float*)d_in[0];   // (4,56,56,256)
    const float* w_qkv  = (const float*)d_in[1];   // (256,768)
    const float* b_qkv  = (const float*)d_in[2];   // (768,)
    const float* rpb    = (const float*)d_in[3];   // (8,49)
    const float* w_proj = (const float*)d_in[4];   // (256,256)
    const float* b_proj = (const float*)d_in[5];   // (256,)
    float* out = (float*)d_out;                    // (4,56,56,256) fp32

    const int M = 12544;

    char* wsp = (char*)d_ws;
    __hip_bfloat16* qf    = (__hip_bfloat16*)wsp; wsp += (size_t)M * 256 * 2;
    __hip_bfloat16* kp    = (__hip_bfloat16*)wsp; wsp += (size_t)4 * 64 * 64 * 256 * 2;
    __hip_bfloat16* vp    = (__hip_bfloat16*)wsp; wsp += (size_t)4 * 64 * 64 * 256 * 2;
    __hip_bfloat16* xb    = (__hip_bfloat16*)wsp; wsp += (size_t)M * 256 * 2;
    __hip_bfloat16* attnb = (__hip_bfloat16*)wsp; wsp += (size_t)M * 256 * 2;
    __hip_bfloat16* wqkvT = (__hip_bfloat16*)wsp; wsp += (size_t)768 * 256 * 2;
    __hip_bfloat16* wprojT= (__hip_bfloat16*)wsp; wsp += (size_t)256 * 256 * 2;

    const float scale = 0.17677669529663689f;  // 32^-0.5

    FParams p;
    p.x = x; p.w_qkv = w_qkv; p.b_qkv = b_qkv; p.rpb = rpb;
    p.w_proj = w_proj; p.b_proj = b_proj; p.out = out;
    p.xb = xb; p.qf = qf; p.kp = kp; p.vp = vp; p.attnb = attnb;
    p.wqkvT = wqkvT; p.wprojT = wprojT; p.qscale = scale;

    // one-time: cooperative-launch support + co-resident grid size
    static int coopGrid = 0;
    static bool inited = false;
    if (!inited) {
        inited = true;
        int dev = 0;
        if (hipGetDevice(&dev) == hipSuccess) {
            int sup = 0, ncu = 0, nb = 0;
            hipDeviceGetAttribute(&sup, hipDeviceAttributeCooperativeLaunch, dev);
            hipDeviceGetAttribute(&ncu, hipDeviceAttributeMultiprocessorCount, dev);
            hipError_t e = hipOccupancyMaxActiveBlocksPerMultiprocessor(
                &nb, (const void*)fused_na2d, 256, 0);
            if (sup && e == hipSuccess && nb > 0 && ncu > 0)
                coopGrid = nb * ncu;           // co-residency guaranteed
        }
    }

    if (coopGrid > 0) {
        void* args[] = { (void*)&p };
        hipError_t e = hipLaunchCooperativeKernel(
            (const void*)fused_na2d, dim3(coopGrid), dim3(256), args, 0, stream);
        if (e == hipSuccess) return;
        (void)hipGetLastError();               // clear, fall through
        coopGrid = 0;                          // don't retry
    }

    // fallback: verified 4-kernel path (R17 behavior)
    prep_k<<<5120, 256, 0, stream>>>(x, xb, w_qkv, wqkvT, w_proj, wprojT, kp, vp);
    gemm_qkv_k<<<dim3(6, 98), 256, 0, stream>>>(xb, wqkvT, b_qkv, qf, kp, vp, scale);
    na2d_attn_k<<<6272, 64, 0, stream>>>(qf, kp, vp, rpb, attnb);
    gemm_proj_k<<<dim3(4, 196), 256, 0, stream>>>(attnb, wprojT, b_proj, out);
}

// Round 5
// 137.912 us; speedup vs baseline: 1.9542x; 1.9542x over previous
//
#include <hip/hip_runtime.h>
#include <hip/hip_bf16.h>

// Shapes (fixed): B=4, H=56, W=56, C=256, NH=8, HD=32, KS=7, PAD=3
// tokens M = 4*56*56 = 12544. Padded k/v planes: [4][64][64][256] bf16,
// interior token (y,x) at plane row y+3, col x+3; border zeroed by prep.
//
// R12: LDS-free direct-fragment GEMM regressed; keep LDS staging.
// R15: attn v-path de-LDS'd -- neutral; kept (lower LDS, 1 vmcnt drain).
// R16: dot2 QK + bf16 qf + packed-f32 PV: 139.8 -> 133.0.
// R17: 2 tokens/wave (2x occupancy): neutral; kept (equal, less regalloc).
// R18: persistent cooperative fusion with grid.sync: 133 -> 270 us. DEAD END
//      (grid.sync stall dominates) but gave ground truth: total real traffic
//      105.6 MB (~17us at BW ceiling), VALU-active ~20us, MFMA ~2.6us. The
//      133us path is ~70% intra-kernel stall, NOT inter-kernel launch gaps.
// R19 (this round): revert to the verified 4-kernel path + fuse x->bf16 into
//      the qkv GEMM A-staging (fp32 global_load_lds, chunk-major LDS layout,
//      cvt after ds_read). Removes xb entirely: net -19.2 MB traffic, prep
//      5120 -> 1984 blocks. RTNE rounding identical -> absmax unchanged.

using frag_ab = __attribute__((ext_vector_type(8))) short;  // 8 bf16 (4 VGPRs)
using f32x4   = __attribute__((ext_vector_type(4))) float;  // 4 fp32 acc
using f32x2   = __attribute__((ext_vector_type(2))) float;  // packed f32 pair

typedef const __attribute__((address_space(1))) unsigned int* gas_u32;
typedef __attribute__((address_space(3))) unsigned int*       las_u32;

__device__ __forceinline__ void gl_lds16(const void* g, void* l) {
    // async global->LDS DMA, 16 B/lane; LDS dst = wave-uniform base + lane*16
    __builtin_amdgcn_global_load_lds((gas_u32)g, (las_u32)l, 16, 0, 0);
}

__device__ __forceinline__ float bflo(unsigned int u) { return __uint_as_float(u << 16); }
__device__ __forceinline__ float bfhi(unsigned int u) { return __uint_as_float(u & 0xffff0000u); }

__device__ __forceinline__ f32x2 unpk2(unsigned int u) {
    f32x2 r; r.x = bflo(u); r.y = bfhi(u); return r;
}

#if defined(__has_builtin)
#if __has_builtin(__builtin_amdgcn_fdot2_f32_bf16)
#define HAVE_FDOT2_BF16 1
#endif
#endif

#ifdef HAVE_FDOT2_BF16
typedef __bf16 bf16x2 __attribute__((ext_vector_type(2)));
__device__ __forceinline__ float dot2bf(unsigned int a, unsigned int b, float c) {
    union { unsigned int u; bf16x2 h; } ua, ub;
    ua.u = a; ub.u = b;
    return __builtin_amdgcn_fdot2_f32_bf16(ua.h, ub.h, c, false);
}
#endif

// ================= prep: weight transposes + pad-border zero ================
// blocks [0,768):     w_qkv [256][768] -> wqkvT [768][256] bf16
// blocks [768,1024):  w_proj [256][256] -> wprojT [256][256] bf16
// blocks [1024,1984): zero the 960 border cols of each padded plane
__global__ __launch_bounds__(256) void prep_k(
    const float* __restrict__ w_qkv,  __hip_bfloat16* __restrict__ wqkvT,
    const float* __restrict__ w_proj, __hip_bfloat16* __restrict__ wprojT,
    __hip_bfloat16* __restrict__ kp,  __hip_bfloat16* __restrict__ vp)
{
    const int bid = blockIdx.x;
    const int tid = threadIdx.x;
    if (bid < 768) {
        const int idx = bid * 256 + tid;          // over 768*256
        const int k = idx & 255, n = idx >> 8;
        wqkvT[idx] = __float2bfloat16(w_qkv[k * 768 + n]);
    } else if (bid < 1024) {
        const int idx = (bid - 768) * 256 + tid;  // over 256*256
        const int k = idx & 255, n = idx >> 8;
        wprojT[idx] = __float2bfloat16(w_proj[k * 256 + n]);
    } else {
        const int u    = (bid - 1024) * 256 + tid;   // over 8*30720
        const int ip   = u / 30720;                  // img*2 + plane
        const int rem  = u - ip * 30720;
        const int cloc = rem >> 5;                   // 0..959 border cells
        const int q16  = rem & 31;                   // 16B chunk of 256 ch
        const int img  = ip >> 1;
        __hip_bfloat16* base = (ip & 1) ? vp : kp;
        int prow, pcol;
        if (cloc < 512) {                            // full pad rows 0-2,59-63
            const int r8 = cloc >> 6;
            prow = (r8 < 3) ? r8 : r8 + 56;
            pcol = cloc & 63;
        } else {                                     // side pads of rows 3..58
            const int c2 = cloc - 512;
            prow = 3 + (c2 >> 3);
            const int cc = c2 & 7;
            pcol = (cc < 3) ? cc : cc + 56;
        }
        *(uint4*)(base + (((size_t)(img * 64 + prow)) * 64 + pcol) * 256 + q16 * 8) =
            make_uint4(0u, 0u, 0u, 0u);
    }
}

// ================= qkv GEMM, 128x128, A read DIRECTLY from fp32 x ===========
// 256 thr = 4 waves; wave w owns quadrant (w>>1, w&1) as 4x4 16x16x32 frags.
// A staged fp32 via global_load_lds into CHUNK-MAJOR layout: per row-block
// [2 chunks][64 frag-lanes][16B]; per-lane global source pre-arranged so the
// linear LDS dest (base + lane*16) lands in fragment order (m173 pattern):
// issue (rb,c): lane l sources row (rb*16 + (l&15)), k = (l>>4)*8 + c*4.
// Read back: 2x ds_read_b128 fp32 at lane*16 (conflict-free) + 8 cvt ->
// frag_ab. RTNE identical to the old separate x->bf16 pass.
__global__ __launch_bounds__(256) void gemm_qkv_k(
    const float* __restrict__ X,                    // (M,256) fp32
    const __hip_bfloat16* __restrict__ BT,          // (768,256) bf16
    const float* __restrict__ bias,
    __hip_bfloat16* __restrict__ qf,
    __hip_bfloat16* __restrict__ kp,
    __hip_bfloat16* __restrict__ vp,
    float qscale)
{
    constexpr int K = 256;
    __shared__ float   Asf[8][2][64][4];   // 16 KB fp32 A
    __shared__ frag_ab Bs[8][64];          //  8 KB bf16 B

    const int tid  = threadIdx.x;
    const int lane = tid & 63;
    const int w    = tid >> 6;
    const int wm   = w >> 1, wn = w & 1;
    const int m0 = blockIdx.y * 128;
    const int n0 = blockIdx.x * 128;

    const int lrow = lane & 15;
    const int lk   = (lane >> 4) * 8;
    // fp32 A source bases: chunk c adds +c*4 floats; K-step adds +k0 floats
    const float* gA0 = X + (size_t)(m0 + (2*w+0)*16 + lrow) * K + lk;
    const float* gA1 = X + (size_t)(m0 + (2*w+1)*16 + lrow) * K + lk;
    const __hip_bfloat16* gB0 = BT + (size_t)(n0 + (2*w+0)*16 + lrow) * K + lk;
    const __hip_bfloat16* gB1 = BT + (size_t)(n0 + (2*w+1)*16 + lrow) * K + lk;

    f32x4 acc[4][4] = {};

    for (int k0 = 0; k0 < K; k0 += 32) {
        gl_lds16(gA0 + k0,     &Asf[2*w+0][0][0][0]);
        gl_lds16(gA0 + k0 + 4, &Asf[2*w+0][1][0][0]);
        gl_lds16(gA1 + k0,     &Asf[2*w+1][0][0][0]);
        gl_lds16(gA1 + k0 + 4, &Asf[2*w+1][1][0][0]);
        gl_lds16(gB0 + k0, &Bs[2*w+0][0]);
        gl_lds16(gB1 + k0, &Bs[2*w+1][0]);
        __syncthreads();
        frag_ab af[4], bf[4];
        #pragma unroll
        for (int i = 0; i < 4; ++i) {
            const float4 c0 = *(const float4*)&Asf[wm*4+i][0][lane][0];
            const float4 c1 = *(const float4*)&Asf[wm*4+i][1][lane][0];
            union { frag_ab f; __hip_bfloat16 h[8]; } u;
            u.h[0] = __float2bfloat16(c0.x); u.h[1] = __float2bfloat16(c0.y);
            u.h[2] = __float2bfloat16(c0.z); u.h[3] = __float2bfloat16(c0.w);
            u.h[4] = __float2bfloat16(c1.x); u.h[5] = __float2bfloat16(c1.y);
            u.h[6] = __float2bfloat16(c1.z); u.h[7] = __float2bfloat16(c1.w);
            af[i] = u.f;
            bf[i] = Bs[wn*4+i][lane];
        }
        #pragma unroll
        for (int i = 0; i < 4; ++i)
            #pragma unroll
            for (int j = 0; j < 4; ++j)
                acc[i][j] = __builtin_amdgcn_mfma_f32_16x16x32_bf16(af[i], bf[j], acc[i][j], 0, 0, 0);
        __syncthreads();
    }

    const int rbase = (lane >> 4) * 4;
    const int cbase = lane & 15;
    #pragma unroll
    for (int fi = 0; fi < 4; ++fi) {
        const int rm = m0 + wm * 64 + fi * 16 + rbase;
        #pragma unroll
        for (int fj = 0; fj < 4; ++fj) {
            const int cn = n0 + wn * 64 + fj * 16 + cbase;
            const float bv = bias[cn];
            #pragma unroll
            for (int r = 0; r < 4; ++r) {
                const int mm  = rm + r;
                const float val = acc[fi][fj][r] + bv;
                const int sel = cn >> 8;                   // 0=q,1=k,2=v
                if (sel == 0) {
                    qf[(size_t)mm * 256 + cn] = __float2bfloat16(val * qscale);
                } else {
                    const int c  = cn & 255;
                    const int bb = mm / 3136;
                    const int r2 = mm % 3136;
                    const int yy = r2 / 56;
                    const int xx = r2 % 56;
                    __hip_bfloat16* dst = (sel == 1) ? kp : vp;
                    dst[(((size_t)(bb * 64 + yy + 3)) * 64 + (xx + 3)) * 256 + c] =
                        __float2bfloat16(val);
                }
            }
        }
    }
}

// ===== proj GEMM, 64x64 tile (R2/R14-validated structure; grid 4x196) ======
__global__ __launch_bounds__(256) void gemm_proj_k(
    const __hip_bfloat16* __restrict__ A,
    const __hip_bfloat16* __restrict__ BT,
    const float* __restrict__ bias,
    float* __restrict__ C)
{
    constexpr int K = 256;
    __shared__ frag_ab As[4][64];   // 4 KB
    __shared__ frag_ab Bs[4][64];   // 4 KB

    const int tid  = threadIdx.x;
    const int lane = tid & 63;
    const int w    = tid >> 6;
    const int wm   = w >> 1, wn = w & 1;
    const int m0 = blockIdx.y * 64;
    const int n0 = blockIdx.x * 64;

    const int lrow = lane & 15;
    const int lk   = (lane >> 4) * 8;
    const __hip_bfloat16* gA = A  + (size_t)(m0 + w * 16 + lrow) * K + lk;
    const __hip_bfloat16* gB = BT + (size_t)(n0 + w * 16 + lrow) * K + lk;

    f32x4 acc[2][2] = {};

    for (int k0 = 0; k0 < K; k0 += 32) {
        gl_lds16(gA + k0, &As[w][0]);
        gl_lds16(gB + k0, &Bs[w][0]);
        __syncthreads();
        const frag_ab a0 = As[2 * wm + 0][lane];
        const frag_ab a1 = As[2 * wm + 1][lane];
        const frag_ab b0 = Bs[2 * wn + 0][lane];
        const frag_ab b1 = Bs[2 * wn + 1][lane];
        acc[0][0] = __builtin_amdgcn_mfma_f32_16x16x32_bf16(a0, b0, acc[0][0], 0, 0, 0);
        acc[0][1] = __builtin_amdgcn_mfma_f32_16x16x32_bf16(a0, b1, acc[0][1], 0, 0, 0);
        acc[1][0] = __builtin_amdgcn_mfma_f32_16x16x32_bf16(a1, b0, acc[1][0], 0, 0, 0);
        acc[1][1] = __builtin_amdgcn_mfma_f32_16x16x32_bf16(a1, b1, acc[1][1], 0, 0, 0);
        __syncthreads();
    }

    const int rbase = (lane >> 4) * 4;
    const int cbase = lane & 15;
    #pragma unroll
    for (int fi = 0; fi < 2; ++fi) {
        const int rm = m0 + wm * 32 + fi * 16 + rbase;
        #pragma unroll
        for (int fj = 0; fj < 2; ++fj) {
            const int cn = n0 + wn * 32 + fj * 16 + cbase;
            const float bv = bias[cn];
            #pragma unroll
            for (int r = 0; r < 4; ++r)
                C[(size_t)(rm + r) * 256 + cn] = acc[fi][fj][r] + bv;
        }
    }
}

// ================= neighborhood attention (R17-verified body) ===============
// ONE WAVE per block = 2 tokens x 8 heads x 4 quarter-heads (8 ch/lane);
// grid 6272. Lane = (tl:1 | h:3 | q:2). EXPLICIT SCALAR staging (R10/R11
// SROA lesson); rolled ky (#pragma unroll 1; R8/R9 spill lesson). NEVER set
// launch_bounds min-waves (R6/R7). XCD swizzle: seg = (bid&7)*784 + (bid>>3).
// k staged via LDS (linear [8][512B], 2 lanes/bank = free); v direct from
// global per lane (R15), issued before the k-prefetch so PV's vmcnt waits
// never drain it.
__global__ __launch_bounds__(64) void na2d_attn_k(
    const __hip_bfloat16* __restrict__ qf,
    const __hip_bfloat16* __restrict__ kp,
    const __hip_bfloat16* __restrict__ vp,
    const float* __restrict__ rpb,
    __hip_bfloat16* __restrict__ out)
{
    const int lane = threadIdx.x;       // 0..63
    const int q8   = lane & 3;          // quarter-head: 8-ch slice
    const int h    = (lane >> 2) & 7;   // head
    const int tl   = (lane >> 5) & 1;   // token within 2-token segment

    const int bid = blockIdx.x;         // 0..6271
    const int seg = (bid & 7) * 784 + (bid >> 3);   // XCD-contiguous remap
    const int row = seg / 28;           // b*56 + y
    const int x0  = (seg % 28) * 2;     // 0..54
    const int b   = row / 56;
    const int y   = row % 56;
    const int t   = row * 56 + x0 + tl;
    const int prow0 = b * 64 + y;       // padded plane row for ky=0

    __shared__ __hip_bfloat16 kbuf[8 * 256];    // 4 KB, linear [8 cols][256 ch]
    __shared__ float srpb[8 * 49];

    for (int i = lane; i < 8 * 49; i += 64) srpb[i] = rpb[i];
    __syncthreads();                    // single-wave barrier: cheap

    // q: 8 bf16 channels, kept PACKED (4 uints)
    unsigned int qpk[4];
    {
        const uint4 qa = *(const uint4*)(qf + (size_t)t * 256 + h * 32 + q8 * 8);
        qpk[0] = qa.x; qpk[1] = qa.y; qpk[2] = qa.z; qpk[3] = qa.w;
    }
#ifndef HAVE_FDOT2_BF16
    f32x2 q2[4];
    #pragma unroll
    for (int i = 0; i < 4; ++i) q2[i] = unpk2(qpk[i]);
#endif

    const int wroff = lane * 16;                    // linear LDS write
    const int rdoff = tl * 512 + h * 64 + q8 * 16;  // + kx*512 per window col

#define GLOAD4(plane, ky, d0, d1, d2, d3)                                       \
    do {                                                                        \
        const char* rb_ = (const char*)((plane) +                               \
            ((size_t)(prow0 + (ky)) * 64 + x0) * 256 + lane * 8);               \
        d0 = *(const uint4*)(rb_);                                              \
        d1 = *(const uint4*)(rb_ + 1024);                                       \
        d2 = *(const uint4*)(rb_ + 2048);                                       \
        d3 = *(const uint4*)(rb_ + 3072);                                       \
    } while (0)

#define LWRITE4(buf, s0, s1, s2, s3)                                            \
    do {                                                                        \
        char* wb_ = (char*)(buf) + wroff;                                       \
        *(uint4*)(wb_)        = s0;                                             \
        *(uint4*)(wb_ + 1024) = s1;                                             \
        *(uint4*)(wb_ + 2048) = s2;                                             \
        *(uint4*)(wb_ + 3072) = s3;                                             \
    } while (0)

    const float* rp = &srpb[h * 49];
    float m = -1e30f, l = 0.f;
    f32x2 o2[4] = {};

    uint4 k0, k1, k2, k3;
    GLOAD4(kp, 0, k0, k1, k2, k3);

    #pragma unroll 1
    for (int ky = 0; ky < 7; ++ky) {
        LWRITE4(kbuf, k0, k1, k2, k3);          // waits vmcnt for k row only
        // per-lane direct v loads: this lane's 8 ch for its 7 cols (R15)
        const __hip_bfloat16* vrow = vp +
            ((size_t)(prow0 + ky) * 64 + x0 + tl) * 256 + h * 32 + q8 * 8;
        uint4 va[7];
        #pragma unroll
        for (int kx = 0; kx < 7; ++kx)
            va[kx] = *(const uint4*)(vrow + kx * 256);
        // k-prefetch AFTER v loads: PV's vmcnt waits never drain it
        if (ky < 6) GLOAD4(kp, ky + 1, k0, k1, k2, k3);
        // ---- 7 row logits from kbuf ----
        float lg[7];
        #pragma unroll
        for (int kx = 0; kx < 7; ++kx) {
            const uint4 w0 = *(const uint4*)((const char*)kbuf + rdoff + kx * 512);
#ifdef HAVE_FDOT2_BF16
            float s = 0.f;
            s = dot2bf(qpk[0], w0.x, s);
            s = dot2bf(qpk[1], w0.y, s);
            s = dot2bf(qpk[2], w0.z, s);
            s = dot2bf(qpk[3], w0.w, s);
#else
            f32x2 s2 = {0.f, 0.f};
            s2 += q2[0] * unpk2(w0.x);
            s2 += q2[1] * unpk2(w0.y);
            s2 += q2[2] * unpk2(w0.z);
            s2 += q2[3] * unpk2(w0.w);
            const float s = s2.x + s2.y;
#endif
            lg[kx] = s;
        }
        // ---- merge quarter-head partials (lanes ^1, ^2) + rpb ----
        #pragma unroll
        for (int kx = 0; kx < 7; ++kx) {
            lg[kx] += __shfl_xor(lg[kx], 1, 64);
            lg[kx] += __shfl_xor(lg[kx], 2, 64);
            lg[kx] += rp[ky * 7 + kx];
        }
        // ---- online softmax update ----
        float rmax = lg[0];
        #pragma unroll
        for (int kx = 1; kx < 7; ++kx) rmax = fmaxf(rmax, lg[kx]);
        const float mnew  = fmaxf(m, rmax);
        const float alpha = __expf(m - mnew);   // ky=0: exp(-inf)=0
        m = mnew;
        l *= alpha;
        const f32x2 alpha2 = {alpha, alpha};
        #pragma unroll
        for (int i = 0; i < 4; ++i) o2[i] *= alpha2;
        // ---- PV from direct-loaded registers, packed-f32 accumulate ----
        #pragma unroll
        for (int kx = 0; kx < 7; ++kx) {
            const float pr = __expf(lg[kx] - mnew);
            l += pr;
            const f32x2 pr2 = {pr, pr};
            const uint4 w0 = va[kx];
            o2[0] += pr2 * unpk2(w0.x);
            o2[1] += pr2 * unpk2(w0.y);
            o2[2] += pr2 * unpk2(w0.z);
            o2[3] += pr2 * unpk2(w0.w);
        }
    }
#undef GLOAD4
#undef LWRITE4

    // ---- store bf16 (feeds proj GEMM) ----
    const float inv = 1.f / l;
    union { uint4 u; __hip_bfloat16 hh[8]; } ob;
    #pragma unroll
    for (int i = 0; i < 4; ++i) {
        ob.hh[2 * i + 0] = __float2bfloat16(o2[i].x * inv);
        ob.hh[2 * i + 1] = __float2bfloat16(o2[i].y * inv);
    }
    *(uint4*)(out + (size_t)t * 256 + h * 32 + q8 * 8) = ob.u;
}

// ===================== host =====================
extern "C" void kernel_launch(void* const* d_in, const int* in_sizes, int n_in,
                              void* d_out, int out_size, void* d_ws, size_t ws_size,
                              hipStream_t stream)
{
    const float* x      = (const float*)d_in[0];   // (4,56,56,256)
    const float* w_qkv  = (const float*)d_in[1];   // (256,768)
    const float* b_qkv  = (const float*)d_in[2];   // (768,)
    const float* rpb    = (const float*)d_in[3];   // (8,49)
    const float* w_proj = (const float*)d_in[4];   // (256,256)
    const float* b_proj = (const float*)d_in[5];   // (256,)
    float* out = (float*)d_out;                    // (4,56,56,256) fp32

    const int M = 12544;

    char* wsp = (char*)d_ws;
    __hip_bfloat16* qf    = (__hip_bfloat16*)wsp; wsp += (size_t)M * 256 * 2;          // 6.4 MB
    __hip_bfloat16* kp    = (__hip_bfloat16*)wsp; wsp += (size_t)4 * 64 * 64 * 256 * 2; // 8.39 MB
    __hip_bfloat16* vp    = (__hip_bfloat16*)wsp; wsp += (size_t)4 * 64 * 64 * 256 * 2; // 8.39 MB
    __hip_bfloat16* attnb = (__hip_bfloat16*)wsp; wsp += (size_t)M * 256 * 2;          // 6.4 MB
    __hip_bfloat16* wqkvT = (__hip_bfloat16*)wsp; wsp += (size_t)768 * 256 * 2;
    __hip_bfloat16* wprojT= (__hip_bfloat16*)wsp; wsp += (size_t)256 * 256 * 2;

    const float scale = 0.17677669529663689f;  // 32^-0.5

    // prep: weight transposes + pad-border zero (x conversion now in-GEMM)
    prep_k<<<1984, 256, 0, stream>>>(w_qkv, wqkvT, w_proj, wprojT, kp, vp);

    // qkv = x @ wqkvT^T + b_qkv (A staged fp32, cvt in-register);
    // q bf16 scaled -> qf; k/v bf16 -> padded planes
    gemm_qkv_k<<<dim3(6, 98), 256, 0, stream>>>(x, wqkvT, b_qkv, qf, kp, vp, scale);

    // attention: 6272 blocks x 64 threads (R17-verified body)
    na2d_attn_k<<<6272, 64, 0, stream>>>(qf, kp, vp, rpb, attnb);

    // out = attnb @ wprojT^T + b_proj (64-tile: 784 blocks ~= 3/CU)
    gemm_proj_k<<<dim3(4, 196), 256, 0, stream>>>(attnb, wprojT, b_proj, out);
}

// Round 6
// 135.386 us; speedup vs baseline: 1.9906x; 1.0187x over previous
//
#include <hip/hip_runtime.h>
#include <hip/hip_bf16.h>

// Shapes (fixed): B=4, H=56, W=56, C=256, NH=8, HD=32, KS=7, PAD=3
// tokens M = 4*56*56 = 12544. Padded k/v planes: [4][64][64][256] bf16,
// interior token (y,x) at plane row y+3, col x+3; border zeroed by prep.
//
// R12: LDS-free direct-fragment GEMM regressed; keep LDS staging.
// R15: attn v-path de-LDS'd -- neutral; kept (lower LDS, 1 vmcnt drain).
// R16: dot2 QK + bf16 qf + packed-f32 PV: 139.8 -> 133.0.
// R17: 2 tokens/wave attn: neutral; kept.
// R18: cooperative grid.sync fusion: 270us DEAD END, but ground truth:
//      VALU-active ~20us, MFMA ~2.6us, HBM ~17us -> the 133us is mostly
//      intra-kernel stall.
// R19: x->bf16 fused into qkv A-staging: +4.6us REGRESSION. Work added
//      inside the qkv k-loop costs more than throughput (2.3 blocks/CU, no
//      overlap); prep savings ~0 (wide memory-bound launch). REVERTED.
// R20 (this round): GEMM k-loops were stage -> barrier(full vmcnt drain,
//      nothing overlapping) -> compute -> barrier: L2 latency serially
//      exposed 8x per block. Now T3-minimum 2-phase (double-buffered LDS,
//      issue next stage BEFORE computing current, ONE barrier per K-step):
//      the compiler's vmcnt(0)-at-barrier drain lands after the MFMAs, so
//      load latency hides under compute. Barriers 16 -> 8 per k-loop.

using frag_ab = __attribute__((ext_vector_type(8))) short;  // 8 bf16 (4 VGPRs)
using f32x4   = __attribute__((ext_vector_type(4))) float;  // 4 fp32 acc
using f32x2   = __attribute__((ext_vector_type(2))) float;  // packed f32 pair

typedef const __attribute__((address_space(1))) unsigned int* gas_u32;
typedef __attribute__((address_space(3))) unsigned int*       las_u32;

__device__ __forceinline__ void gl_lds16(const void* g, void* l) {
    // async global->LDS DMA, 16 B/lane; LDS dst = wave-uniform base + lane*16
    __builtin_amdgcn_global_load_lds((gas_u32)g, (las_u32)l, 16, 0, 0);
}

__device__ __forceinline__ float bflo(unsigned int u) { return __uint_as_float(u << 16); }
__device__ __forceinline__ float bfhi(unsigned int u) { return __uint_as_float(u & 0xffff0000u); }

__device__ __forceinline__ f32x2 unpk2(unsigned int u) {
    f32x2 r; r.x = bflo(u); r.y = bfhi(u); return r;
}

#if defined(__has_builtin)
#if __has_builtin(__builtin_amdgcn_fdot2_f32_bf16)
#define HAVE_FDOT2_BF16 1
#endif
#endif

#ifdef HAVE_FDOT2_BF16
typedef __bf16 bf16x2 __attribute__((ext_vector_type(2)));
__device__ __forceinline__ float dot2bf(unsigned int a, unsigned int b, float c) {
    union { unsigned int u; bf16x2 h; } ua, ub;
    ua.u = a; ub.u = b;
    return __builtin_amdgcn_fdot2_f32_bf16(ua.h, ub.h, c, false);
}
#endif

// ================= fused prep =================
// blocks [0,3136):    x fp32 -> xb bf16 (float4/thread)
// blocks [3136,3904): w_qkv [256][768] -> wqkvT [768][256] bf16
// blocks [3904,4160): w_proj [256][256] -> wprojT [256][256] bf16
// blocks [4160,5120): zero the 960 border cols of each padded plane
__global__ __launch_bounds__(256) void prep_k(
    const float* __restrict__ x,      __hip_bfloat16* __restrict__ xb,
    const float* __restrict__ w_qkv,  __hip_bfloat16* __restrict__ wqkvT,
    const float* __restrict__ w_proj, __hip_bfloat16* __restrict__ wprojT,
    __hip_bfloat16* __restrict__ kp,  __hip_bfloat16* __restrict__ vp)
{
    const int bid = blockIdx.x;
    const int tid = threadIdx.x;
    if (bid < 3136) {
        const int i = bid * 256 + tid;            // over M*256/4 = 802816
        const float4 v = ((const float4*)x)[i];
        union { ushort4 u; __hip_bfloat16 h[4]; } o;
        o.h[0] = __float2bfloat16(v.x); o.h[1] = __float2bfloat16(v.y);
        o.h[2] = __float2bfloat16(v.z); o.h[3] = __float2bfloat16(v.w);
        ((ushort4*)xb)[i] = o.u;
    } else if (bid < 3904) {
        const int idx = (bid - 3136) * 256 + tid; // over 768*256
        const int k = idx & 255, n = idx >> 8;
        wqkvT[idx] = __float2bfloat16(w_qkv[k * 768 + n]);
    } else if (bid < 4160) {
        const int idx = (bid - 3904) * 256 + tid; // over 256*256
        const int k = idx & 255, n = idx >> 8;
        wprojT[idx] = __float2bfloat16(w_proj[k * 256 + n]);
    } else {
        const int u    = (bid - 4160) * 256 + tid;   // over 8*30720
        const int ip   = u / 30720;                  // img*2 + plane
        const int rem  = u - ip * 30720;
        const int cloc = rem >> 5;                   // 0..959 border cells
        const int q16  = rem & 31;                   // 16B chunk of 256 ch
        const int img  = ip >> 1;
        __hip_bfloat16* base = (ip & 1) ? vp : kp;
        int prow, pcol;
        if (cloc < 512) {                            // full pad rows 0-2,59-63
            const int r8 = cloc >> 6;
            prow = (r8 < 3) ? r8 : r8 + 56;
            pcol = cloc & 63;
        } else {                                     // side pads of rows 3..58
            const int c2 = cloc - 512;
            prow = 3 + (c2 >> 3);
            const int cc = c2 & 7;
            pcol = (cc < 3) ? cc : cc + 56;
        }
        *(uint4*)(base + (((size_t)(img * 64 + prow)) * 64 + pcol) * 256 + q16 * 8) =
            make_uint4(0u, 0u, 0u, 0u);
    }
}

// ================= qkv GEMM, 128x128, 2-phase double-buffered (R20) =========
// 256 thr = 4 waves; wave w owns quadrant (w>>1, w&1) as 4x4 16x16x32 frags.
// Wave w stages A row-blocks 2w,2w+1 and B row-blocks 2w,2w+1 in fragment
// order via global_load_lds. Pipeline: stage(buf0); barrier; per K-step t:
// {issue stage(buf[t+1]); ds_read+MFMA from buf[t]; barrier}. The barrier's
// vmcnt(0) drain overlaps the MFMA block that precedes it.
__global__ __launch_bounds__(256) void gemm_qkv_k(
    const __hip_bfloat16* __restrict__ A,       // xb (M,256) bf16
    const __hip_bfloat16* __restrict__ BT,      // wqkvT (768,256) bf16
    const float* __restrict__ bias,
    __hip_bfloat16* __restrict__ qf,
    __hip_bfloat16* __restrict__ kp,
    __hip_bfloat16* __restrict__ vp,
    float qscale)
{
    constexpr int K = 256;
    __shared__ frag_ab As[2][8][64];   // 16 KB
    __shared__ frag_ab Bs[2][8][64];   // 16 KB

    const int tid  = threadIdx.x;
    const int lane = tid & 63;
    const int w    = tid >> 6;
    const int wm   = w >> 1, wn = w & 1;
    const int m0 = blockIdx.y * 128;
    const int n0 = blockIdx.x * 128;

    const int lrow = lane & 15;
    const int lk   = (lane >> 4) * 8;
    const __hip_bfloat16* gA0 = A  + (size_t)(m0 + (2*w+0)*16 + lrow) * K + lk;
    const __hip_bfloat16* gA1 = A  + (size_t)(m0 + (2*w+1)*16 + lrow) * K + lk;
    const __hip_bfloat16* gB0 = BT + (size_t)(n0 + (2*w+0)*16 + lrow) * K + lk;
    const __hip_bfloat16* gB1 = BT + (size_t)(n0 + (2*w+1)*16 + lrow) * K + lk;

    f32x4 acc[4][4] = {};

    // prologue: stage K-step 0 into buf 0
    gl_lds16(gA0, &As[0][2*w+0][0]);
    gl_lds16(gA1, &As[0][2*w+1][0]);
    gl_lds16(gB0, &Bs[0][2*w+0][0]);
    gl_lds16(gB1, &Bs[0][2*w+1][0]);
    __syncthreads();

    #pragma unroll 1
    for (int t = 0; t < 8; ++t) {
        const int cur = t & 1;
        if (t < 7) {                       // issue next stage BEFORE compute
            const int k0 = (t + 1) * 32;
            const int nxt = cur ^ 1;
            gl_lds16(gA0 + k0, &As[nxt][2*w+0][0]);
            gl_lds16(gA1 + k0, &As[nxt][2*w+1][0]);
            gl_lds16(gB0 + k0, &Bs[nxt][2*w+0][0]);
            gl_lds16(gB1 + k0, &Bs[nxt][2*w+1][0]);
        }
        frag_ab af[4], bf[4];
        #pragma unroll
        for (int i = 0; i < 4; ++i) {
            af[i] = As[cur][wm*4+i][lane];
            bf[i] = Bs[cur][wn*4+i][lane];
        }
        #pragma unroll
        for (int i = 0; i < 4; ++i)
            #pragma unroll
            for (int j = 0; j < 4; ++j)
                acc[i][j] = __builtin_amdgcn_mfma_f32_16x16x32_bf16(af[i], bf[j], acc[i][j], 0, 0, 0);
        __syncthreads();                   // drains next stage; overlapped w/ MFMA
    }

    const int rbase = (lane >> 4) * 4;
    const int cbase = lane & 15;
    #pragma unroll
    for (int fi = 0; fi < 4; ++fi) {
        const int rm = m0 + wm * 64 + fi * 16 + rbase;
        #pragma unroll
        for (int fj = 0; fj < 4; ++fj) {
            const int cn = n0 + wn * 64 + fj * 16 + cbase;
            const float bv = bias[cn];
            #pragma unroll
            for (int r = 0; r < 4; ++r) {
                const int mm  = rm + r;
                const float val = acc[fi][fj][r] + bv;
                const int sel = cn >> 8;                   // 0=q,1=k,2=v
                if (sel == 0) {
                    qf[(size_t)mm * 256 + cn] = __float2bfloat16(val * qscale);
                } else {
                    const int c  = cn & 255;
                    const int bb = mm / 3136;
                    const int r2 = mm % 3136;
                    const int yy = r2 / 56;
                    const int xx = r2 % 56;
                    __hip_bfloat16* dst = (sel == 1) ? kp : vp;
                    dst[(((size_t)(bb * 64 + yy + 3)) * 64 + (xx + 3)) * 256 + c] =
                        __float2bfloat16(val);
                }
            }
        }
    }
}

// ===== proj GEMM, 64x64 tile, 2-phase double-buffered (R20) =================
__global__ __launch_bounds__(256) void gemm_proj_k(
    const __hip_bfloat16* __restrict__ A,
    const __hip_bfloat16* __restrict__ BT,
    const float* __restrict__ bias,
    float* __restrict__ C)
{
    constexpr int K = 256;
    __shared__ frag_ab As[2][4][64];   // 8 KB
    __shared__ frag_ab Bs[2][4][64];   // 8 KB

    const int tid  = threadIdx.x;
    const int lane = tid & 63;
    const int w    = tid >> 6;
    const int wm   = w >> 1, wn = w & 1;
    const int m0 = blockIdx.y * 64;
    const int n0 = blockIdx.x * 64;

    const int lrow = lane & 15;
    const int lk   = (lane >> 4) * 8;
    const __hip_bfloat16* gA = A  + (size_t)(m0 + w * 16 + lrow) * K + lk;
    const __hip_bfloat16* gB = BT + (size_t)(n0 + w * 16 + lrow) * K + lk;

    f32x4 acc[2][2] = {};

    gl_lds16(gA, &As[0][w][0]);
    gl_lds16(gB, &Bs[0][w][0]);
    __syncthreads();

    #pragma unroll 1
    for (int t = 0; t < 8; ++t) {
        const int cur = t & 1;
        if (t < 7) {
            const int k0 = (t + 1) * 32;
            const int nxt = cur ^ 1;
            gl_lds16(gA + k0, &As[nxt][w][0]);
            gl_lds16(gB + k0, &Bs[nxt][w][0]);
        }
        const frag_ab a0 = As[cur][2 * wm + 0][lane];
        const frag_ab a1 = As[cur][2 * wm + 1][lane];
        const frag_ab b0 = Bs[cur][2 * wn + 0][lane];
        const frag_ab b1 = Bs[cur][2 * wn + 1][lane];
        acc[0][0] = __builtin_amdgcn_mfma_f32_16x16x32_bf16(a0, b0, acc[0][0], 0, 0, 0);
        acc[0][1] = __builtin_amdgcn_mfma_f32_16x16x32_bf16(a0, b1, acc[0][1], 0, 0, 0);
        acc[1][0] = __builtin_amdgcn_mfma_f32_16x16x32_bf16(a1, b0, acc[1][0], 0, 0, 0);
        acc[1][1] = __builtin_amdgcn_mfma_f32_16x16x32_bf16(a1, b1, acc[1][1], 0, 0, 0);
        __syncthreads();
    }

    const int rbase = (lane >> 4) * 4;
    const int cbase = lane & 15;
    #pragma unroll
    for (int fi = 0; fi < 2; ++fi) {
        const int rm = m0 + wm * 32 + fi * 16 + rbase;
        #pragma unroll
        for (int fj = 0; fj < 2; ++fj) {
            const int cn = n0 + wn * 32 + fj * 16 + cbase;
            const float bv = bias[cn];
            #pragma unroll
            for (int r = 0; r < 4; ++r)
                C[(size_t)(rm + r) * 256 + cn] = acc[fi][fj][r] + bv;
        }
    }
}

// ================= neighborhood attention (R17-verified body) ===============
// ONE WAVE per block = 2 tokens x 8 heads x 4 quarter-heads (8 ch/lane);
// grid 6272. Lane = (tl:1 | h:3 | q:2). EXPLICIT SCALAR staging (R10/R11
// SROA lesson); rolled ky (#pragma unroll 1; R8/R9 spill lesson). NEVER set
// launch_bounds min-waves (R6/R7). XCD swizzle: seg = (bid&7)*784 + (bid>>3).
// k staged via LDS (linear [8][512B], 2 lanes/bank = free); v direct from
// global per lane (R15), issued before the k-prefetch so PV's vmcnt waits
// never drain it.
__global__ __launch_bounds__(64) void na2d_attn_k(
    const __hip_bfloat16* __restrict__ qf,
    const __hip_bfloat16* __restrict__ kp,
    const __hip_bfloat16* __restrict__ vp,
    const float* __restrict__ rpb,
    __hip_bfloat16* __restrict__ out)
{
    const int lane = threadIdx.x;       // 0..63
    const int q8   = lane & 3;          // quarter-head: 8-ch slice
    const int h    = (lane >> 2) & 7;   // head
    const int tl   = (lane >> 5) & 1;   // token within 2-token segment

    const int bid = blockIdx.x;         // 0..6271
    const int seg = (bid & 7) * 784 + (bid >> 3);   // XCD-contiguous remap
    const int row = seg / 28;           // b*56 + y
    const int x0  = (seg % 28) * 2;     // 0..54
    const int b   = row / 56;
    const int y   = row % 56;
    const int t   = row * 56 + x0 + tl;
    const int prow0 = b * 64 + y;       // padded plane row for ky=0

    __shared__ __hip_bfloat16 kbuf[8 * 256];    // 4 KB, linear [8 cols][256 ch]
    __shared__ float srpb[8 * 49];

    for (int i = lane; i < 8 * 49; i += 64) srpb[i] = rpb[i];
    __syncthreads();                    // single-wave barrier: cheap

    // q: 8 bf16 channels, kept PACKED (4 uints)
    unsigned int qpk[4];
    {
        const uint4 qa = *(const uint4*)(qf + (size_t)t * 256 + h * 32 + q8 * 8);
        qpk[0] = qa.x; qpk[1] = qa.y; qpk[2] = qa.z; qpk[3] = qa.w;
    }
#ifndef HAVE_FDOT2_BF16
    f32x2 q2[4];
    #pragma unroll
    for (int i = 0; i < 4; ++i) q2[i] = unpk2(qpk[i]);
#endif

    const int wroff = lane * 16;                    // linear LDS write
    const int rdoff = tl * 512 + h * 64 + q8 * 16;  // + kx*512 per window col

#define GLOAD4(plane, ky, d0, d1, d2, d3)                                       \
    do {                                                                        \
        const char* rb_ = (const char*)((plane) +                               \
            ((size_t)(prow0 + (ky)) * 64 + x0) * 256 + lane * 8);               \
        d0 = *(const uint4*)(rb_);                                              \
        d1 = *(const uint4*)(rb_ + 1024);                                       \
        d2 = *(const uint4*)(rb_ + 2048);                                       \
        d3 = *(const uint4*)(rb_ + 3072);                                       \
    } while (0)

#define LWRITE4(buf, s0, s1, s2, s3)                                            \
    do {                                                                        \
        char* wb_ = (char*)(buf) + wroff;                                       \
        *(uint4*)(wb_)        = s0;                                             \
        *(uint4*)(wb_ + 1024) = s1;                                             \
        *(uint4*)(wb_ + 2048) = s2;                                             \
        *(uint4*)(wb_ + 3072) = s3;                                             \
    } while (0)

    const float* rp = &srpb[h * 49];
    float m = -1e30f, l = 0.f;
    f32x2 o2[4] = {};

    uint4 k0, k1, k2, k3;
    GLOAD4(kp, 0, k0, k1, k2, k3);

    #pragma unroll 1
    for (int ky = 0; ky < 7; ++ky) {
        LWRITE4(kbuf, k0, k1, k2, k3);          // waits vmcnt for k row only
        // per-lane direct v loads: this lane's 8 ch for its 7 cols (R15)
        const __hip_bfloat16* vrow = vp +
            ((size_t)(prow0 + ky) * 64 + x0 + tl) * 256 + h * 32 + q8 * 8;
        uint4 va[7];
        #pragma unroll
        for (int kx = 0; kx < 7; ++kx)
            va[kx] = *(const uint4*)(vrow + kx * 256);
        // k-prefetch AFTER v loads: PV's vmcnt waits never drain it
        if (ky < 6) GLOAD4(kp, ky + 1, k0, k1, k2, k3);
        // ---- 7 row logits from kbuf ----
        float lg[7];
        #pragma unroll
        for (int kx = 0; kx < 7; ++kx) {
            const uint4 w0 = *(const uint4*)((const char*)kbuf + rdoff + kx * 512);
#ifdef HAVE_FDOT2_BF16
            float s = 0.f;
            s = dot2bf(qpk[0], w0.x, s);
            s = dot2bf(qpk[1], w0.y, s);
            s = dot2bf(qpk[2], w0.z, s);
            s = dot2bf(qpk[3], w0.w, s);
#else
            f32x2 s2 = {0.f, 0.f};
            s2 += q2[0] * unpk2(w0.x);
            s2 += q2[1] * unpk2(w0.y);
            s2 += q2[2] * unpk2(w0.z);
            s2 += q2[3] * unpk2(w0.w);
            const float s = s2.x + s2.y;
#endif
            lg[kx] = s;
        }
        // ---- merge quarter-head partials (lanes ^1, ^2) + rpb ----
        #pragma unroll
        for (int kx = 0; kx < 7; ++kx) {
            lg[kx] += __shfl_xor(lg[kx], 1, 64);
            lg[kx] += __shfl_xor(lg[kx], 2, 64);
            lg[kx] += rp[ky * 7 + kx];
        }
        // ---- online softmax update ----
        float rmax = lg[0];
        #pragma unroll
        for (int kx = 1; kx < 7; ++kx) rmax = fmaxf(rmax, lg[kx]);
        const float mnew  = fmaxf(m, rmax);
        const float alpha = __expf(m - mnew);   // ky=0: exp(-inf)=0
        m = mnew;
        l *= alpha;
        const f32x2 alpha2 = {alpha, alpha};
        #pragma unroll
        for (int i = 0; i < 4; ++i) o2[i] *= alpha2;
        // ---- PV from direct-loaded registers, packed-f32 accumulate ----
        #pragma unroll
        for (int kx = 0; kx < 7; ++kx) {
            const float pr = __expf(lg[kx] - mnew);
            l += pr;
            const f32x2 pr2 = {pr, pr};
            const uint4 w0 = va[kx];
            o2[0] += pr2 * unpk2(w0.x);
            o2[1] += pr2 * unpk2(w0.y);
            o2[2] += pr2 * unpk2(w0.z);
            o2[3] += pr2 * unpk2(w0.w);
        }
    }
#undef GLOAD4
#undef LWRITE4

    // ---- store bf16 (feeds proj GEMM) ----
    const float inv = 1.f / l;
    union { uint4 u; __hip_bfloat16 hh[8]; } ob;
    #pragma unroll
    for (int i = 0; i < 4; ++i) {
        ob.hh[2 * i + 0] = __float2bfloat16(o2[i].x * inv);
        ob.hh[2 * i + 1] = __float2bfloat16(o2[i].y * inv);
    }
    *(uint4*)(out + (size_t)t * 256 + h * 32 + q8 * 8) = ob.u;
}

// ===================== host =====================
extern "C" void kernel_launch(void* const* d_in, const int* in_sizes, int n_in,
                              void* d_out, int out_size, void* d_ws, size_t ws_size,
                              hipStream_t stream)
{
    const float* x      = (const float*)d_in[0];   // (4,56,56,256)
    const float* w_qkv  = (const float*)d_in[1];   // (256,768)
    const float* b_qkv  = (const float*)d_in[2];   // (768,)
    const float* rpb    = (const float*)d_in[3];   // (8,49)
    const float* w_proj = (const float*)d_in[4];   // (256,256)
    const float* b_proj = (const float*)d_in[5];   // (256,)
    float* out = (float*)d_out;                    // (4,56,56,256) fp32

    const int M = 12544;

    char* wsp = (char*)d_ws;
    __hip_bfloat16* qf    = (__hip_bfloat16*)wsp; wsp += (size_t)M * 256 * 2;          // 6.4 MB
    __hip_bfloat16* kp    = (__hip_bfloat16*)wsp; wsp += (size_t)4 * 64 * 64 * 256 * 2; // 8.39 MB
    __hip_bfloat16* vp    = (__hip_bfloat16*)wsp; wsp += (size_t)4 * 64 * 64 * 256 * 2; // 8.39 MB
    __hip_bfloat16* xb    = (__hip_bfloat16*)wsp; wsp += (size_t)M * 256 * 2;
    __hip_bfloat16* attnb = (__hip_bfloat16*)wsp; wsp += (size_t)M * 256 * 2;
    __hip_bfloat16* wqkvT = (__hip_bfloat16*)wsp; wsp += (size_t)768 * 256 * 2;
    __hip_bfloat16* wprojT= (__hip_bfloat16*)wsp; wsp += (size_t)256 * 256 * 2;

    const float scale = 0.17677669529663689f;  // 32^-0.5

    // fused prep: x->bf16, both weight transposes, pad-border zero of kp/vp
    prep_k<<<5120, 256, 0, stream>>>(x, xb, w_qkv, wqkvT, w_proj, wprojT, kp, vp);

    // qkv = xb @ wqkvT^T + b_qkv (2-phase pipelined);
    // q bf16 scaled -> qf; k/v bf16 -> padded planes
    gemm_qkv_k<<<dim3(6, 98), 256, 0, stream>>>(xb, wqkvT, b_qkv, qf, kp, vp, scale);

    // attention: 6272 blocks x 64 threads (R17-verified body)
    na2d_attn_k<<<6272, 64, 0, stream>>>(qf, kp, vp, rpb, attnb);

    // out = attnb @ wprojT^T + b_proj (64-tile, 2-phase pipelined)
    gemm_proj_k<<<dim3(4, 196), 256, 0, stream>>>(attnb, wprojT, b_proj, out);
}